// Round 1
// baseline (443.244 us; speedup 1.0000x reference)
//
#include <hip/hip_runtime.h>

#define LEAKY 0.2f

static inline int ceil_div(int a, int b) { return (a + b - 1) / b; }

// ---------------- CSR build ----------------

__global__ __launch_bounds__(256) void count_kernel(const int* __restrict__ dst,
                                                    int* __restrict__ counts, int E) {
    int i = blockIdx.x * 256 + threadIdx.x;
    if (i < E) atomicAdd(&counts[dst[i]], 1);
}

// tile = 1024 elements per block (256 threads x 4)
__global__ __launch_bounds__(256) void scan_phase1(const int* __restrict__ counts,
                                                   int* __restrict__ rowstart,
                                                   int* __restrict__ tilesums, int n) {
    __shared__ int sdata[256];
    int t = threadIdx.x;
    int base = blockIdx.x * 1024 + t * 4;
    int v[4];
    int s = 0;
#pragma unroll
    for (int j = 0; j < 4; ++j) {
        int idx = base + j;
        v[j] = (idx < n) ? counts[idx] : 0;
        s += v[j];
    }
    sdata[t] = s;
    __syncthreads();
    for (int off = 1; off < 256; off <<= 1) {
        int x = (t >= off) ? sdata[t - off] : 0;
        __syncthreads();
        sdata[t] += x;
        __syncthreads();
    }
    int excl = sdata[t] - s;  // exclusive prefix of this thread's chunk
    if (t == 255) tilesums[blockIdx.x] = sdata[255];
    int run = excl;
#pragma unroll
    for (int j = 0; j < 4; ++j) {
        int idx = base + j;
        if (idx < n) rowstart[idx] = run;
        run += v[j];
    }
}

__global__ __launch_bounds__(256) void scan_phase2(int* __restrict__ tilesums, int nt) {
    __shared__ int sdata[256];
    int t = threadIdx.x;
    int v = (t < nt) ? tilesums[t] : 0;
    sdata[t] = v;
    __syncthreads();
    for (int off = 1; off < 256; off <<= 1) {
        int x = (t >= off) ? sdata[t - off] : 0;
        __syncthreads();
        sdata[t] += x;
        __syncthreads();
    }
    if (t < nt) tilesums[t] = sdata[t] - v;  // exclusive
}

__global__ __launch_bounds__(256) void scan_phase3(int* __restrict__ rowstart,
                                                   const int* __restrict__ tileoffs,
                                                   int n, int total) {
    int add = tileoffs[blockIdx.x];
    int base = blockIdx.x * 1024 + threadIdx.x * 4;
#pragma unroll
    for (int j = 0; j < 4; ++j) {
        int idx = base + j;
        if (idx < n) rowstart[idx] += add;
    }
    if (blockIdx.x == 0 && threadIdx.x == 0) rowstart[n] = total;
}

__global__ __launch_bounds__(256) void scatter_kernel(const int* __restrict__ src,
                                                      const int* __restrict__ dst,
                                                      const int* __restrict__ rowstart,
                                                      int* __restrict__ cursor,
                                                      int* __restrict__ bucket, int E) {
    int i = blockIdx.x * 256 + threadIdx.x;
    if (i < E) {
        int d = dst[i];
        int p = atomicAdd(&cursor[d], 1);
        bucket[rowstart[d] + p] = src[i];  // store SRC node id directly
    }
}

// ---------------- GEMM + attention coefficients ----------------
// feat[n][c] = sum_k in[n][k] * W[k][c];  el[n][h] = sum_d feat*al, er likewise.
// block: 32 rows x 128 cols; thread: col c = tid&127, 16 rows.
__global__ __launch_bounds__(256) void gemm_attn(const float* __restrict__ in,
                                                 const float* __restrict__ W,
                                                 const float* __restrict__ al,
                                                 const float* __restrict__ ar,
                                                 float* __restrict__ feat,
                                                 float* __restrict__ el,
                                                 float* __restrict__ er, int N) {
    __shared__ float sIn[32][128];
    int tid = threadIdx.x;
    int c = tid & 127;
    int rgroup = tid >> 7;  // 0 or 1
    int blockrow = blockIdx.x * 32;

    for (int i = tid; i < 32 * 128; i += 256) {
        int r = i >> 7;
        int row = blockrow + r;
        sIn[r][i & 127] = (row < N) ? in[row * 128 + (i & 127)] : 0.0f;
    }
    __syncthreads();

    float acc[16];
#pragma unroll
    for (int r = 0; r < 16; ++r) acc[r] = 0.0f;
    int r0 = rgroup * 16;

    for (int k = 0; k < 128; k += 4) {
        float w0 = W[(k + 0) * 128 + c];
        float w1 = W[(k + 1) * 128 + c];
        float w2 = W[(k + 2) * 128 + c];
        float w3 = W[(k + 3) * 128 + c];
#pragma unroll
        for (int r = 0; r < 16; ++r) {
            float4 f = *reinterpret_cast<const float4*>(&sIn[r0 + r][k]);  // wave-uniform broadcast
            acc[r] += f.x * w0 + f.y * w1 + f.z * w2 + f.w * w3;
        }
    }

    int h = c >> 4;
    int d = c & 15;
    float alv = al[c];
    float arv = ar[c];
#pragma unroll
    for (int r = 0; r < 16; ++r) {
        int row = blockrow + r0 + r;
        if (row < N) {  // wave-uniform branch (row depends only on rgroup/blockIdx)
            feat[row * 128 + c] = acc[r];
            float pl = acc[r] * alv;
            float pr = acc[r] * arv;
#pragma unroll
            for (int off = 8; off; off >>= 1) {
                pl += __shfl_xor(pl, off);
                pr += __shfl_xor(pr, off);
            }
            if (d == 0) {
                el[row * 8 + h] = pl;
                er[row * 8 + h] = pr;
            }
        }
    }
}

// ---------------- per-dst-node softmax + aggregation (atomic-free) ----------------
// one wave per node; lane owns components 2*lane, 2*lane+1; head h = lane>>3.
__global__ __launch_bounds__(256) void aggregate(const float* __restrict__ feat,
                                                 const float* __restrict__ el,
                                                 const float* __restrict__ er,
                                                 const int* __restrict__ rowstart,
                                                 const int* __restrict__ bucket,
                                                 const float* __restrict__ bias,
                                                 float* __restrict__ out, int N, int do_relu) {
    int wid = (blockIdx.x * 256 + threadIdx.x) >> 6;
    int lane = threadIdx.x & 63;
    if (wid >= N) return;
    int n = wid;
    int h = lane >> 3;
    float er_h = er[n * 8 + h];
    int beg = rowstart[n];
    int end = rowstart[n + 1];

    float l = 0.0f;
    float ax = 0.0f, ay = 0.0f;
    for (int j = beg; j < end; ++j) {
        int s = bucket[j];
        float e = el[s * 8 + h] + er_h;
        e = (e > 0.0f) ? e : LEAKY * e;
        float p = __expf(e);  // no max-shift needed: |e| small, exp safe in f32
        l += p;
        float2 f = *reinterpret_cast<const float2*>(feat + s * 128 + lane * 2);
        ax += p * f.x;
        ay += p * f.y;
    }
    float inv = (end > beg) ? 1.0f / l : 0.0f;
    int c = lane * 2;
    float ox = ax * inv + bias[c];
    float oy = ay * inv + bias[c + 1];
    if (do_relu) {
        ox = fmaxf(ox, 0.0f);
        oy = fmaxf(oy, 0.0f);
    }
    float2 o = {ox, oy};
    *reinterpret_cast<float2*>(out + n * 128 + c) = o;
}

// ---------------- readout ----------------

__global__ __launch_bounds__(256) void mean_reduce(const float* __restrict__ h,
                                                   float* __restrict__ meanbuf, int N) {
    int c = threadIdx.x & 127;
    int rbase = blockIdx.x * 2 + (threadIdx.x >> 7);
    float s = 0.0f;
    for (int r = rbase; r < N; r += gridDim.x * 2) s += h[r * 128 + c];
    atomicAdd(&meanbuf[c], s);
}

__global__ __launch_bounds__(64) void classifier(const float* __restrict__ meanbuf,
                                                 const float* __restrict__ Wc,
                                                 const float* __restrict__ bc,
                                                 float* __restrict__ outp, float invN) {
    int j = threadIdx.x;
    if (j < 10) {
        float s = 0.0f;
        for (int k = 0; k < 128; ++k) s += meanbuf[k] * invN * Wc[k * 10 + j];
        outp[j] = s + bc[j];
    }
}

// ---------------- launch ----------------

extern "C" void kernel_launch(void* const* d_in, const int* in_sizes, int n_in,
                              void* d_out, int out_size, void* d_ws, size_t ws_size,
                              hipStream_t stream) {
    const float* x   = (const float*)d_in[0];
    const int*   src = (const int*)d_in[1];
    const int*   dst = (const int*)d_in[2];
    const float* W1  = (const float*)d_in[3];
    const float* al1 = (const float*)d_in[4];
    const float* ar1 = (const float*)d_in[5];
    const float* b1  = (const float*)d_in[6];
    const float* W2  = (const float*)d_in[7];
    const float* al2 = (const float*)d_in[8];
    const float* ar2 = (const float*)d_in[9];
    const float* b2  = (const float*)d_in[10];
    const float* Wc  = (const float*)d_in[11];
    const float* bc  = (const float*)d_in[12];

    int N = in_sizes[0] / 128;
    int E = in_sizes[1];

    size_t off = 0;
    auto alloc = [&](size_t bytes) -> void* {
        void* p = (char*)d_ws + off;
        off += (bytes + 255) & ~size_t(255);
        return p;
    };
    int*   counts   = (int*)alloc(sizeof(int) * N);
    int*   rowstart = (int*)alloc(sizeof(int) * (N + 1));
    int*   cursor   = (int*)alloc(sizeof(int) * N);
    int*   tilesums = (int*)alloc(sizeof(int) * 256);
    int*   bucket   = (int*)alloc(sizeof(int) * E);
    float* feat     = (float*)alloc(sizeof(float) * (size_t)N * 128);
    float* el       = (float*)alloc(sizeof(float) * N * 8);
    float* er       = (float*)alloc(sizeof(float) * N * 8);
    float* h1       = (float*)alloc(sizeof(float) * (size_t)N * 128);
    float* h2       = (float*)alloc(sizeof(float) * (size_t)N * 128);
    float* meanbuf  = (float*)alloc(sizeof(float) * 128);

    hipMemsetAsync(counts, 0, sizeof(int) * N, stream);
    hipMemsetAsync(cursor, 0, sizeof(int) * N, stream);
    hipMemsetAsync(meanbuf, 0, sizeof(float) * 128, stream);

    int numTiles = (N + 1023) / 1024;  // 49 for N=50000

    count_kernel<<<ceil_div(E, 256), 256, 0, stream>>>(dst, counts, E);
    scan_phase1<<<numTiles, 256, 0, stream>>>(counts, rowstart, tilesums, N);
    scan_phase2<<<1, 256, 0, stream>>>(tilesums, numTiles);
    scan_phase3<<<numTiles, 256, 0, stream>>>(rowstart, tilesums, N, E);
    scatter_kernel<<<ceil_div(E, 256), 256, 0, stream>>>(src, dst, rowstart, cursor, bucket, E);

    // layer 1
    gemm_attn<<<ceil_div(N, 32), 256, 0, stream>>>(x, W1, al1, ar1, feat, el, er, N);
    aggregate<<<ceil_div(N * 64, 256), 256, 0, stream>>>(feat, el, er, rowstart, bucket, b1, h1, N, 1);
    // layer 2
    gemm_attn<<<ceil_div(N, 32), 256, 0, stream>>>(h1, W2, al2, ar2, feat, el, er, N);
    aggregate<<<ceil_div(N * 64, 256), 256, 0, stream>>>(feat, el, er, rowstart, bucket, b2, h2, N, 0);
    // readout
    mean_reduce<<<256, 256, 0, stream>>>(h2, meanbuf, N);
    classifier<<<1, 64, 0, stream>>>(meanbuf, Wc, bc, (float*)d_out, 1.0f / (float)N);
}